// Round 24
// baseline (311.928 us; speedup 1.0000x reference)
//
#include <hip/hip_runtime.h>
#include <stdint.h>

namespace {

constexpr int Tn = 512;
constexpr int Sn = 256;
constexpr float EPS = 1e-12f;

typedef _Float16 f16x8 __attribute__((ext_vector_type(8)));
typedef float    f32x4 __attribute__((ext_vector_type(4)));

// Barrier that drains ONLY lgkmcnt (LDS), never vmcnt (T4 pattern).
__device__ __forceinline__ void wg_barrier_lds() {
    asm volatile("s_waitcnt lgkmcnt(0)" ::: "memory");
    __builtin_amdgcn_s_barrier();
}

__launch_bounds__(256, 1)
__global__ void hmm_kernel(const float* __restrict__ emission,  // [B,T,S]
                           const float* __restrict__ weight,    // [S,S]
                           const float* __restrict__ init,      // [S]
                           float* __restrict__ out)             // [B,T,S]
{
    const int tid  = threadIdx.x;      // 0..255 == carried column
    const int wv   = tid >> 6;         // wave 0..3: owns cols 64wv .. 64wv+63
    const int lane = tid & 63;
    const int g    = lane >> 4;        // k-lane-group 0..3 (also my col-set)
    const int jj   = lane & 15;
    const int b    = blockIdx.x;       // batch row

    __shared__ __align__(16) _Float16 wf16[2][Sn];   // dbuf w~ image (f16)
    __shared__ __align__(16) float    s_m[Sn];
    __shared__ __align__(16) float    s_z[Sn];

    // ---- prologue 1: transition softmax row stats (thread j owns row j) ----
    {
        const float* wr = weight + (size_t)tid * Sn;
        float m = -3.402823466e38f;
        #pragma unroll 4
        for (int i = 0; i < Sn; i += 4) {
            float4 v = *reinterpret_cast<const float4*>(wr + i);
            m = fmaxf(m, fmaxf(fmaxf(v.x, v.y), fmaxf(v.z, v.w)));
        }
        float z0 = 0.f, z1 = 0.f, z2 = 0.f, z3 = 0.f;
        #pragma unroll 4
        for (int i = 0; i < Sn; i += 4) {
            float4 v = *reinterpret_cast<const float4*>(wr + i);
            z0 += expf(v.x - m); z1 += expf(v.y - m);
            z2 += expf(v.z - m); z3 += expf(v.w - m);
        }
        s_m[tid] = m;
        s_z[tid] = 1.f / ((z0 + z1) + (z2 + z3));
        __syncthreads();
    }

    // ---- prologue 2: persistent B fragments, 4 col-sets per wave (f16) ----
    // Shared k-convention with A: chunk ck, group g, elem i <-> k = ck*32+g*8+i.
    // bf[s][ck] covers column 64*wv + 16*s + jj.
    f16x8 bf[4][8];
    #pragma unroll
    for (int s = 0; s < 4; ++s) {
        const int col = 64 * wv + 16 * s + jj;
        #pragma unroll
        for (int ck = 0; ck < 8; ++ck) {
            #pragma unroll
            for (int i = 0; i < 8; ++i) {
                const int k = ck * 32 + g * 8 + i;
                bf[s][ck][i] =
                    (_Float16)(expf(weight[(size_t)k * Sn + col] - s_m[k]) * s_z[k]);
            }
        }
    }
    // all-ones B operand: D = sum_k A[m,k] -> l1 in reg0 of EVERY lane
    const f16x8 ones8 = {(_Float16)1.f, (_Float16)1.f, (_Float16)1.f, (_Float16)1.f,
                         (_Float16)1.f, (_Float16)1.f, (_Float16)1.f, (_Float16)1.f};

    // ---- prologue 3: initial state softmax -> w~_0 image, e_1 ----
    const float* em = emission + (size_t)b * Tn * Sn + tid;
    float*       op = out      + (size_t)b * Tn * Sn + tid;
    {
        float i0 = init[lane], i1 = init[lane + 64],
              i2 = init[lane + 128], i3 = init[lane + 192];
        float mx = fmaxf(fmaxf(i0, i1), fmaxf(i2, i3));
        #pragma unroll
        for (int o = 32; o >= 1; o >>= 1) mx = fmaxf(mx, __shfl_xor(mx, o));
        float zz = expf(i0 - mx) + expf(i1 - mx) + expf(i2 - mx) + expf(i3 - mx);
        #pragma unroll
        for (int o = 32; o >= 1; o >>= 1) zz += __shfl_xor(zz, o);
        float u  = expf(init[tid] - mx) / zz;
        wf16[0][tid] = (_Float16)(u * em[0]);
    }
    float enext = em[Sn];          // e_1[tid]
    __syncthreads();

#define MFMA(A, B, D) __builtin_amdgcn_mfma_f32_16x16x32_f16((A), (B), (D), 0, 0, 0)

    #pragma unroll 1
    for (int t = 0; t < Tn; ++t) {
        const int p = t & 1;

        // (1) load ALL af fragments first — 8 ds_read_b128 in flight at once
        f16x8 af[8];
        #pragma unroll
        for (int ck = 0; ck < 8; ++ck)
            af[ck] = *reinterpret_cast<const f16x8*>(&wf16[p][ck * 32 + g * 8]);
        __builtin_amdgcn_sched_barrier(0);

        // (2) 10 independent 4-deep MFMA chains (was 5 × 8-deep):
        //     *a accumulates ck=0..3, *b accumulates ck=4..7.
        //     dS pair issued first so l1's chain completes earliest.
        f32x4 d0a = {0,0,0,0}, d1a = {0,0,0,0}, d2a = {0,0,0,0}, d3a = {0,0,0,0};
        f32x4 d0b = {0,0,0,0}, d1b = {0,0,0,0}, d2b = {0,0,0,0}, d3b = {0,0,0,0};
        f32x4 dSa = {0,0,0,0}, dSb = {0,0,0,0};
        #pragma unroll
        for (int ck = 0; ck < 4; ++ck) {
            dSa = MFMA(af[ck],     ones8,        dSa);
            dSb = MFMA(af[ck + 4], ones8,        dSb);
            d0a = MFMA(af[ck],     bf[0][ck],     d0a);
            d0b = MFMA(af[ck + 4], bf[0][ck + 4], d0b);
            d1a = MFMA(af[ck],     bf[1][ck],     d1a);
            d1b = MFMA(af[ck + 4], bf[1][ck + 4], d1b);
            d2a = MFMA(af[ck],     bf[2][ck],     d2a);
            d2b = MFMA(af[ck + 4], bf[2][ck + 4], d2b);
            d3a = MFMA(af[ck],     bf[3][ck],     d3a);
            d3b = MFMA(af[ck + 4], bf[3][ck + 4], d3b);
        }

        // row-broadcast A => reg0 of chain s holds the partial y[64wv+16s+jj];
        // my carried column tid = 64wv+16g+jj => pick chain s = g, sum halves.
        float ya = (g == 0) ? d0a[0] : (g == 1) ? d1a[0] : (g == 2) ? d2a[0] : d3a[0];
        float yb = (g == 0) ? d0b[0] : (g == 1) ? d1b[0] : (g == 2) ? d2b[0] : d3b[0];
        float y  = ya + yb;
        float l1 = fmaxf(dSa[0] + dSb[0], EPS);

        // exact power-of-2 rescale from THIS step's l1
        uint32_t ebits = __float_as_uint(l1) & 0x7f800000u;
        float sigma = __uint_as_float(0x7f000000u - ebits);

        // Bayes update + image write (critical tail)
        float wn = (y * sigma) * enext;          // w~_{t+1}[tid]
        wf16[p ^ 1][tid] = (_Float16)wn;

        // output store — off the lgkm path, vmcnt untouched
        op[(size_t)t * Sn] = y * (1.f / l1);

        // prefetch e_{t+2}
        const int tp = (t + 2 < Tn) ? (t + 2) : (Tn - 1);
        enext = em[(size_t)tp * Sn];

        wg_barrier_lds();     // single lgkm-only barrier per step
    }

#undef MFMA
}

} // namespace

extern "C" void kernel_launch(void* const* d_in, const int* in_sizes, int n_in,
                              void* d_out, int out_size, void* d_ws, size_t ws_size,
                              hipStream_t stream) {
    const float* emission = (const float*)d_in[0];
    const float* weight   = (const float*)d_in[1];
    const float* init     = (const float*)d_in[2];
    float* outp = (float*)d_out;
    const int Bn = in_sizes[0] / (Tn * Sn);   // 128 for the reference shapes

    hipLaunchKernelGGL(hmm_kernel, dim3(Bn), dim3(256), 0, stream,
                       emission, weight, init, outp);
}

// Round 25
// 279.422 us; speedup vs baseline: 1.1163x; 1.1163x over previous
//
#include <hip/hip_runtime.h>
#include <stdint.h>

namespace {

constexpr int Tn = 512;
constexpr int Sn = 256;
constexpr float EPS = 1e-12f;

typedef _Float16 f16x8 __attribute__((ext_vector_type(8)));
typedef float    f32x4 __attribute__((ext_vector_type(4)));

// Barrier that drains ONLY lgkmcnt (LDS), never vmcnt (T4 pattern).
__device__ __forceinline__ void wg_barrier_lds() {
    asm volatile("s_waitcnt lgkmcnt(0)" ::: "memory");
    __builtin_amdgcn_s_barrier();
}

__launch_bounds__(256, 1)
__global__ void hmm_kernel(const float* __restrict__ emission,  // [B,T,S]
                           const float* __restrict__ weight,    // [S,S]
                           const float* __restrict__ init,      // [S]
                           float* __restrict__ out)             // [B,T,S]
{
    const int tid  = threadIdx.x;      // 0..255 == carried column
    const int wv   = tid >> 6;         // wave 0..3: owns cols 64wv .. 64wv+63
    const int lane = tid & 63;
    const int g    = lane >> 4;        // k-lane-group 0..3 (also my col-set)
    const int jj   = lane & 15;
    const int b    = blockIdx.x;       // batch row

    __shared__ __align__(16) _Float16 wf16[2][Sn];   // dbuf w~ image (f16)
    __shared__ __align__(16) float    s_m[Sn];
    __shared__ __align__(16) float    s_z[Sn];

    // ---- prologue 1: transition softmax row stats (thread j owns row j) ----
    {
        const float* wr = weight + (size_t)tid * Sn;
        float m = -3.402823466e38f;
        #pragma unroll 4
        for (int i = 0; i < Sn; i += 4) {
            float4 v = *reinterpret_cast<const float4*>(wr + i);
            m = fmaxf(m, fmaxf(fmaxf(v.x, v.y), fmaxf(v.z, v.w)));
        }
        float z0 = 0.f, z1 = 0.f, z2 = 0.f, z3 = 0.f;
        #pragma unroll 4
        for (int i = 0; i < Sn; i += 4) {
            float4 v = *reinterpret_cast<const float4*>(wr + i);
            z0 += expf(v.x - m); z1 += expf(v.y - m);
            z2 += expf(v.z - m); z3 += expf(v.w - m);
        }
        s_m[tid] = m;
        s_z[tid] = 1.f / ((z0 + z1) + (z2 + z3));
        __syncthreads();
    }

    // ---- prologue 2: persistent B fragments, 4 col-sets per wave (f16) ----
    // Shared k-convention with A: chunk ck, group g, elem i <-> k = ck*32+g*8+i.
    // bf[s][ck] covers column 64*wv + 16*s + jj.
    f16x8 bf[4][8];
    #pragma unroll
    for (int s = 0; s < 4; ++s) {
        const int col = 64 * wv + 16 * s + jj;
        #pragma unroll
        for (int ck = 0; ck < 8; ++ck) {
            #pragma unroll
            for (int i = 0; i < 8; ++i) {
                const int k = ck * 32 + g * 8 + i;
                bf[s][ck][i] =
                    (_Float16)(expf(weight[(size_t)k * Sn + col] - s_m[k]) * s_z[k]);
            }
        }
    }
    // all-ones B operand: D = sum_k A[m,k] -> l1 in reg0 of EVERY lane
    const f16x8 ones8 = {(_Float16)1.f, (_Float16)1.f, (_Float16)1.f, (_Float16)1.f,
                         (_Float16)1.f, (_Float16)1.f, (_Float16)1.f, (_Float16)1.f};

    // ---- prologue 3: initial state softmax -> w~_0 image, e_1 ----
    const float* em = emission + (size_t)b * Tn * Sn + tid;
    float*       op = out      + (size_t)b * Tn * Sn + tid;
    {
        float i0 = init[lane], i1 = init[lane + 64],
              i2 = init[lane + 128], i3 = init[lane + 192];
        float mx = fmaxf(fmaxf(i0, i1), fmaxf(i2, i3));
        #pragma unroll
        for (int o = 32; o >= 1; o >>= 1) mx = fmaxf(mx, __shfl_xor(mx, o));
        float zz = expf(i0 - mx) + expf(i1 - mx) + expf(i2 - mx) + expf(i3 - mx);
        #pragma unroll
        for (int o = 32; o >= 1; o >>= 1) zz += __shfl_xor(zz, o);
        float u  = expf(init[tid] - mx) / zz;
        wf16[0][tid] = (_Float16)(u * em[0]);
    }
    float enext = em[Sn];          // e_1[tid]
    __syncthreads();

#define MFMA(A, B, D) __builtin_amdgcn_mfma_f32_16x16x32_f16((A), (B), (D), 0, 0, 0)

    #pragma unroll 1
    for (int t = 0; t < Tn; ++t) {
        const int p = t & 1;

        // (1) load ALL af fragments first — 8 ds_read_b128 in flight at once.
        // We are grid-limited (1 block/CU), so the extra 32 VGPRs are free;
        // without this the allocator serialized read->wait->MFMA 8 times.
        f16x8 af[8];
        #pragma unroll
        for (int ck = 0; ck < 8; ++ck)
            af[ck] = *reinterpret_cast<const f16x8*>(&wf16[p][ck * 32 + g * 8]);

        // (2) pin: no MFMA may be scheduled before the loads are all issued
        __builtin_amdgcn_sched_barrier(0);

        // (3) 5 MFMA chains (4 col-sets + ones)
        f32x4 d0 = {0.f,0.f,0.f,0.f}, d1 = {0.f,0.f,0.f,0.f};
        f32x4 d2 = {0.f,0.f,0.f,0.f}, d3 = {0.f,0.f,0.f,0.f};
        f32x4 dS = {0.f,0.f,0.f,0.f};
        #pragma unroll
        for (int ck = 0; ck < 8; ++ck) {
            d0 = MFMA(af[ck], bf[0][ck], d0);
            d1 = MFMA(af[ck], bf[1][ck], d1);
            d2 = MFMA(af[ck], bf[2][ck], d2);
            d3 = MFMA(af[ck], bf[3][ck], d3);
            dS = MFMA(af[ck], ones8, dS);
        }

        // row-broadcast A => reg0 of each chain holds y[64wv+16s+jj];
        // my carried column tid = 64wv + 16g + jj  =>  pick chain s = g.
        float y  = (g == 0) ? d0[0] : (g == 1) ? d1[0] : (g == 2) ? d2[0] : d3[0];
        float l1 = fmaxf(dS[0], EPS);

        // exact power-of-2 rescale from THIS step's l1
        uint32_t ebits = __float_as_uint(l1) & 0x7f800000u;
        float sigma = __uint_as_float(0x7f000000u - ebits);

        // Bayes update + image write (critical tail)
        float wn = (y * sigma) * enext;          // w~_{t+1}[tid]
        wf16[p ^ 1][tid] = (_Float16)wn;

        // output store — off the lgkm path, vmcnt untouched
        op[(size_t)t * Sn] = y * (1.f / l1);

        // prefetch e_{t+2}
        const int tp = (t + 2 < Tn) ? (t + 2) : (Tn - 1);
        enext = em[(size_t)tp * Sn];

        wg_barrier_lds();     // single lgkm-only barrier per step
    }

#undef MFMA
}

} // namespace

extern "C" void kernel_launch(void* const* d_in, const int* in_sizes, int n_in,
                              void* d_out, int out_size, void* d_ws, size_t ws_size,
                              hipStream_t stream) {
    const float* emission = (const float*)d_in[0];
    const float* weight   = (const float*)d_in[1];
    const float* init     = (const float*)d_in[2];
    float* outp = (float*)d_out;
    const int Bn = in_sizes[0] / (Tn * Sn);   // 128 for the reference shapes

    hipLaunchKernelGGL(hmm_kernel, dim3(Bn), dim3(256), 0, stream,
                       emission, weight, init, outp);
}